// Round 5
// baseline (390.775 us; speedup 1.0000x reference)
//
#include <hip/hip_runtime.h>
#include <hip/hip_bf16.h>

#define D 128
#define CHUNK 1024   // elements per scan block (256 thr x 4)

typedef __attribute__((ext_vector_type(8))) short bf16x8;
typedef __attribute__((ext_vector_type(4))) float f32x4;
typedef __attribute__((ext_vector_type(4))) unsigned int u32x4;

// ---- bf16 helpers (bit-level, RNE via __float2bfloat16) --------------------
__device__ inline float bflo(unsigned u) { return __uint_as_float(u << 16); }
__device__ inline float bfhi(unsigned u) { return __uint_as_float(u & 0xffff0000u); }
__device__ inline unsigned short f2bf(float f) {
    __hip_bfloat16 h = __float2bfloat16(f);
    return *reinterpret_cast<unsigned short*>(&h);
}
__device__ inline unsigned pack2bf(float lo, float hi) {
    return (unsigned)f2bf(lo) | ((unsigned)f2bf(hi) << 16);
}

// ---------------------------------------------------------------------------
// fp32 -> bf16 conversion
// ---------------------------------------------------------------------------
__global__ __launch_bounds__(256) void tobf16_kernel(
    const float* __restrict__ x, unsigned short* __restrict__ y, int n4)
{
    int i = blockIdx.x * blockDim.x + threadIdx.x;
    int stride = gridDim.x * blockDim.x;
    for (; i < n4; i += stride) {
        float4 v = *reinterpret_cast<const float4*>(&x[(size_t)i * 4]);
        uint2 o;
        o.x = pack2bf(v.x, v.y);
        o.y = pack2bf(v.z, v.w);
        *reinterpret_cast<uint2*>(&y[(size_t)i * 4]) = o;
    }
}

// ---------------------------------------------------------------------------
// Phase A: CSR build. off[] is IMMUTABLE after scan3 (R3-proven dataflow);
// scan3 also initializes cur[] = off[] so scatter needs only ONE atomic RMW
// per edge-direction (no extra random off[d] read).
// ---------------------------------------------------------------------------
__global__ __launch_bounds__(256) void hist_kernel(
    const int* __restrict__ src, const int* __restrict__ dst,
    int* __restrict__ cnt, int E, int N)
{
    int i = blockIdx.x * blockDim.x + threadIdx.x;
    int stride = gridDim.x * blockDim.x;
    for (int e = i; e < E; e += stride) {
        atomicAdd(&cnt[dst[e]], 1);
        atomicAdd(&cnt[N + src[e]], 1);
    }
}

__global__ __launch_bounds__(256) void scan1_kernel(
    const int* __restrict__ cnt, int* __restrict__ blk, int n2)
{
    __shared__ int red[256];
    const int b = blockIdx.x, t = threadIdx.x;
    const int base = b * CHUNK + t * 4;
    int s = 0;
    if (base + 3 < n2) {
        int4 v = *reinterpret_cast<const int4*>(&cnt[base]);
        s = v.x + v.y + v.z + v.w;
    } else {
        for (int j = 0; j < 4; ++j) { int idx = base + j; if (idx < n2) s += cnt[idx]; }
    }
    red[t] = s; __syncthreads();
    for (int o = 128; o > 0; o >>= 1) { if (t < o) red[t] += red[t + o]; __syncthreads(); }
    if (t == 0) blk[b] = red[0];
}

__global__ __launch_bounds__(256) void scan2_kernel(int* __restrict__ blk, int NB)
{
    __shared__ int sh[256];
    const int t = threadIdx.x;
    sh[t] = (t < NB) ? blk[t] : 0;
    __syncthreads();
    for (int o = 1; o < 256; o <<= 1) {
        int v = (t >= o) ? sh[t - o] : 0;
        __syncthreads();
        sh[t] += v;
        __syncthreads();
    }
    if (t < NB) blk[t] = (t > 0) ? sh[t - 1] : 0;   // exclusive
}

__global__ __launch_bounds__(256) void scan3_kernel(
    const int* __restrict__ cnt, const int* __restrict__ blk,
    int* __restrict__ off, int* __restrict__ cur, int n2, int total)
{
    __shared__ int sh[256];
    const int b = blockIdx.x, t = threadIdx.x;
    const int base = b * CHUNK + t * 4;
    int v[4]; int s = 0;
    for (int j = 0; j < 4; ++j) { int idx = base + j; v[j] = (idx < n2) ? cnt[idx] : 0; s += v[j]; }
    sh[t] = s; __syncthreads();
    for (int o = 1; o < 256; o <<= 1) {
        int x = (t >= o) ? sh[t - o] : 0;
        __syncthreads();
        sh[t] += x;
        __syncthreads();
    }
    int excl = blk[b] + ((t > 0) ? sh[t - 1] : 0);
    for (int j = 0; j < 4; ++j) {
        int idx = base + j;
        if (idx < n2) { off[idx] = excl; cur[idx] = excl; }
        excl += v[j];
    }
    if (b == 0 && t == 0) off[n2] = total;
}

// ---------------------------------------------------------------------------
// Scatter edge ids. One atomic per edge-direction on cur[] (pre-initialized
// to segment starts by scan3); off[] stays immutable for the gather.
// ---------------------------------------------------------------------------
__global__ __launch_bounds__(256) void scatter_ids_kernel(
    const int* __restrict__ src, const int* __restrict__ dst,
    int* __restrict__ cur, int* __restrict__ csr, int E, int N)
{
    int i = blockIdx.x * blockDim.x + threadIdx.x;
    int stride = gridDim.x * blockDim.x;
    for (int e = i; e < E; e += stride) {
        const int s = src[e], d = dst[e];
        int p = atomicAdd(&cur[d], 1);
        csr[p] = s;
        int p2 = atomicAdd(&cur[N + s], 1);
        csr[p2] = d;
    }
}

// ---------------------------------------------------------------------------
// Phase B: gather means in bf16. 16 lanes per segment; lane l owns bf16
// columns [8l, 8l+8). Bounds from IMMUTABLE off (R3-proven). Streaming data
// (csr reads, meanb writes) marked non-temporal so featb stays L2-resident.
// ---------------------------------------------------------------------------
__global__ __launch_bounds__(256) void gather_mean_kernel(
    const unsigned short* __restrict__ featb, const int* __restrict__ off,
    const int* __restrict__ csr, unsigned short* __restrict__ meanb, int n2)
{
    const int tid = blockIdx.x * 256 + threadIdx.x;
    const int seg = tid >> 4;
    const int l = tid & 15;
    if (seg >= n2) return;

    const int beg = off[seg], end = off[seg + 1];
    float a0=0,a1=0,a2=0,a3=0,a4=0,a5=0,a6=0,a7=0;

    int e = beg;
    for (; e + 1 < end; e += 2) {
        const int n0 = __builtin_nontemporal_load(&csr[e]);
        const int n1 = __builtin_nontemporal_load(&csr[e + 1]);
        const uint4 v0 = *reinterpret_cast<const uint4*>(featb + (size_t)n0 * D + l * 8);
        const uint4 v1 = *reinterpret_cast<const uint4*>(featb + (size_t)n1 * D + l * 8);
        a0 += bflo(v0.x) + bflo(v1.x); a1 += bfhi(v0.x) + bfhi(v1.x);
        a2 += bflo(v0.y) + bflo(v1.y); a3 += bfhi(v0.y) + bfhi(v1.y);
        a4 += bflo(v0.z) + bflo(v1.z); a5 += bfhi(v0.z) + bfhi(v1.z);
        a6 += bflo(v0.w) + bflo(v1.w); a7 += bfhi(v0.w) + bfhi(v1.w);
    }
    if (e < end) {
        const int n0 = __builtin_nontemporal_load(&csr[e]);
        const uint4 v0 = *reinterpret_cast<const uint4*>(featb + (size_t)n0 * D + l * 8);
        a0 += bflo(v0.x); a1 += bfhi(v0.x);
        a2 += bflo(v0.y); a3 += bfhi(v0.y);
        a4 += bflo(v0.z); a5 += bfhi(v0.z);
        a6 += bflo(v0.w); a7 += bfhi(v0.w);
    }

    const int deg = end - beg;
    const float inv = 1.0f / (float)((deg > 1) ? deg : 1);
    u32x4 o;
    o.x = pack2bf(a0 * inv, a1 * inv);
    o.y = pack2bf(a2 * inv, a3 * inv);
    o.z = pack2bf(a4 * inv, a5 * inv);
    o.w = pack2bf(a6 * inv, a7 * inv);
    __builtin_nontemporal_store(o, reinterpret_cast<u32x4*>(meanb + (size_t)seg * D + l * 8));
}

// ---------------------------------------------------------------------------
// Phase C: bf16 MFMA GEMM (m89-verified C/D layout). out stores non-temporal.
// ---------------------------------------------------------------------------
__global__ __launch_bounds__(256) void mfma_gemm_kernel(
    const unsigned short* __restrict__ featb,
    const unsigned short* __restrict__ meanb,
    const unsigned short* __restrict__ Wb,      // [128][384] bf16
    float* __restrict__ out, int N)
{
    const int t = threadIdx.x;
    const int wv = t >> 6;
    const int lane = t & 63;
    const int r = lane & 15;
    const int kb = (lane >> 4) * 8;

    const int row0 = blockIdx.x * 64 + wv * 16;
    const int row = row0 + r;
    const int rowc = (row < N) ? row : (N - 1);

    f32x4 acc[8];
#pragma unroll
    for (int n = 0; n < 8; ++n) acc[n] = (f32x4){0.f, 0.f, 0.f, 0.f};

    const unsigned short* h0 = featb + (size_t)rowc * D;
    const unsigned short* h1 = meanb + (size_t)rowc * D;
    const unsigned short* h2 = meanb + ((size_t)N + rowc) * D;

#pragma unroll
    for (int k0 = 0; k0 < 384; k0 += 32) {
        const unsigned short* hs = (k0 < 128) ? h0 : (k0 < 256) ? h1 : h2;
        const int ko = (k0 & 127) + kb;
        const bf16x8 a = *reinterpret_cast<const bf16x8*>(hs + ko);
#pragma unroll
        for (int n = 0; n < 8; ++n) {
            const int c = n * 16 + r;
            const bf16x8 b = *reinterpret_cast<const bf16x8*>(Wb + (size_t)c * 384 + k0 + kb);
            acc[n] = __builtin_amdgcn_mfma_f32_16x16x32_bf16(a, b, acc[n], 0, 0, 0);
        }
    }

    const int ro = row0 + (lane >> 4) * 4;
#pragma unroll
    for (int n = 0; n < 8; ++n) {
        const int c = n * 16 + r;
#pragma unroll
        for (int i = 0; i < 4; ++i) {
            const int rr2 = ro + i;
            if (rr2 < N)
                __builtin_nontemporal_store(fmaxf(acc[n][i], 0.0f),
                                            &out[(size_t)rr2 * D + c]);
        }
    }
}

// ---------------------------------------------------------------------------
extern "C" void kernel_launch(void* const* d_in, const int* in_sizes, int n_in,
                              void* d_out, int out_size, void* d_ws, size_t ws_size,
                              hipStream_t stream) {
    const float* feat = (const float*)d_in[0];
    const float* W    = (const float*)d_in[1];
    const int*   ei   = (const int*)d_in[2];
    float*       out  = (float*)d_out;

    const int E = in_sizes[2] / 2;           // 800000
    const int N = in_sizes[0] / D;           // 100000
    const int n2 = 2 * N;
    const int* src = ei;
    const int* dst = ei + E;

    // ws layout (4B units then 2B units, all 16B-aligned):
    // cnt[n2] | cur[n2] | off[n2+4] | blk[256] | csr[2E] |
    // featb[N*D] u16 | Wb[128*384] u16 | meanb[n2*D] u16
    int* cnt = (int*)d_ws;
    int* cur = cnt + n2;
    int* off = cur + n2;
    int* blk = off + (n2 + 4);
    int* csr = blk + 256;
    unsigned short* featb = (unsigned short*)(csr + 2 * E);
    unsigned short* Wb    = featb + (size_t)N * D;
    unsigned short* meanb = Wb + 128 * 384;

    // zero cnt only (cur is fully initialized by scan3, off by scan3)
    hipMemsetAsync(cnt, 0, (size_t)n2 * sizeof(int), stream);

    const int NB = (n2 + CHUNK - 1) / CHUNK; // 196

    tobf16_kernel<<<2048, 256, 0, stream>>>(feat, featb, N * D / 4);
    tobf16_kernel<<<48, 256, 0, stream>>>(W, Wb, 128 * 384 / 4);

    hist_kernel<<<2048, 256, 0, stream>>>(src, dst, cnt, E, N);
    scan1_kernel<<<NB, 256, 0, stream>>>(cnt, blk, n2);
    scan2_kernel<<<1, 256, 0, stream>>>(blk, NB);
    scan3_kernel<<<NB, 256, 0, stream>>>(cnt, blk, off, cur, n2, 2 * E);
    scatter_ids_kernel<<<2048, 256, 0, stream>>>(src, dst, cur, csr, E, N);

    const int gather_blocks = (n2 * 16 + 255) / 256;   // 16 lanes per segment
    gather_mean_kernel<<<gather_blocks, 256, 0, stream>>>(featb, off, csr, meanb, n2);

    mfma_gemm_kernel<<<(N + 63) / 64, 256, 0, stream>>>(featb, meanb, Wb, out, N);
}

// Round 6
// 329.370 us; speedup vs baseline: 1.1864x; 1.1864x over previous
//
#include <hip/hip_runtime.h>
#include <hip/hip_bf16.h>

#define D 128
#define CHUNK 1024   // elements per scan block (256 thr x 4)
#define NXCD 8

typedef __attribute__((ext_vector_type(8))) short bf16x8;
typedef __attribute__((ext_vector_type(4))) float f32x4;

// ---- bf16 helpers (bit-level, RNE via __float2bfloat16) --------------------
__device__ inline float bflo(unsigned u) { return __uint_as_float(u << 16); }
__device__ inline float bfhi(unsigned u) { return __uint_as_float(u & 0xffff0000u); }
__device__ inline unsigned short f2bf(float f) {
    __hip_bfloat16 h = __float2bfloat16(f);
    return *reinterpret_cast<unsigned short*>(&h);
}
__device__ inline unsigned pack2bf(float lo, float hi) {
    return (unsigned)f2bf(lo) | ((unsigned)f2bf(hi) << 16);
}

// ---------------------------------------------------------------------------
// fp32 -> bf16 conversion
// ---------------------------------------------------------------------------
__global__ __launch_bounds__(256) void tobf16_kernel(
    const float* __restrict__ x, unsigned short* __restrict__ y, int n4)
{
    int i = blockIdx.x * blockDim.x + threadIdx.x;
    int stride = gridDim.x * blockDim.x;
    for (; i < n4; i += stride) {
        float4 v = *reinterpret_cast<const float4*>(&x[(size_t)i * 4]);
        uint2 o;
        o.x = pack2bf(v.x, v.y);
        o.y = pack2bf(v.z, v.w);
        *reinterpret_cast<uint2*>(&y[(size_t)i * 4]) = o;
    }
}

// ---------------------------------------------------------------------------
// Phase A: CSR build. off[] is IMMUTABLE after scan3 (plain-stored, plain-
// read: safe pattern). cur[] is initialized by scan3, atomically RMW'd by
// scatter, and DEAD afterwards (never plain-read later: safe pattern).
// ---------------------------------------------------------------------------
__global__ __launch_bounds__(256) void hist_kernel(
    const int* __restrict__ src, const int* __restrict__ dst,
    int* __restrict__ cnt, int E, int N)
{
    int i = blockIdx.x * blockDim.x + threadIdx.x;
    int stride = gridDim.x * blockDim.x;
    for (int e = i; e < E; e += stride) {
        atomicAdd(&cnt[dst[e]], 1);
        atomicAdd(&cnt[N + src[e]], 1);
    }
}

__global__ __launch_bounds__(256) void scan1_kernel(
    const int* __restrict__ cnt, int* __restrict__ blk, int n2)
{
    __shared__ int red[256];
    const int b = blockIdx.x, t = threadIdx.x;
    const int base = b * CHUNK + t * 4;
    int s = 0;
    if (base + 3 < n2) {
        int4 v = *reinterpret_cast<const int4*>(&cnt[base]);
        s = v.x + v.y + v.z + v.w;
    } else {
        for (int j = 0; j < 4; ++j) { int idx = base + j; if (idx < n2) s += cnt[idx]; }
    }
    red[t] = s; __syncthreads();
    for (int o = 128; o > 0; o >>= 1) { if (t < o) red[t] += red[t + o]; __syncthreads(); }
    if (t == 0) blk[b] = red[0];
}

__global__ __launch_bounds__(256) void scan2_kernel(int* __restrict__ blk, int NB)
{
    __shared__ int sh[256];
    const int t = threadIdx.x;
    sh[t] = (t < NB) ? blk[t] : 0;
    __syncthreads();
    for (int o = 1; o < 256; o <<= 1) {
        int v = (t >= o) ? sh[t - o] : 0;
        __syncthreads();
        sh[t] += v;
        __syncthreads();
    }
    if (t < NB) blk[t] = (t > 0) ? sh[t - 1] : 0;   // exclusive
}

__global__ __launch_bounds__(256) void scan3_kernel(
    const int* __restrict__ cnt, const int* __restrict__ blk,
    int* __restrict__ off, int* __restrict__ cur, int n2, int total)
{
    __shared__ int sh[256];
    const int b = blockIdx.x, t = threadIdx.x;
    const int base = b * CHUNK + t * 4;
    int v[4]; int s = 0;
    for (int j = 0; j < 4; ++j) { int idx = base + j; v[j] = (idx < n2) ? cnt[idx] : 0; s += v[j]; }
    sh[t] = s; __syncthreads();
    for (int o = 1; o < 256; o <<= 1) {
        int x = (t >= o) ? sh[t - o] : 0;
        __syncthreads();
        sh[t] += x;
        __syncthreads();
    }
    int excl = blk[b] + ((t > 0) ? sh[t - 1] : 0);
    for (int j = 0; j < 4; ++j) {
        int idx = base + j;
        if (idx < n2) { off[idx] = excl; cur[idx] = excl; }
        excl += v[j];
    }
    if (b == 0 && t == 0) off[n2] = total;
}

// ---------------------------------------------------------------------------
// Scatter edge ids, node-range partitioned for XCD write locality.
// Block group g = blockIdx.x & 7 owns nodes [g*npr, (g+1)*npr): under the
// round-robin block->XCD dispatch, each ~800KB csr region is plain-stored by
// ONE XCD, so 64B lines assemble fully in that XCD's L2 before writeback
// (~6.4MB instead of 16x-amplified ~107MB). Each group redundantly reads the
// full edge list (L2/L3-resident). Correctness does NOT depend on the XCD
// mapping: each edge-direction is processed exactly once by the unique group
// owning its segment, and csr/off follow the plain-store->plain-read pattern
// proven in R3/R5.
// ---------------------------------------------------------------------------
__global__ __launch_bounds__(256) void scatter_ids_kernel(
    const int* __restrict__ src, const int* __restrict__ dst,
    int* __restrict__ cur, int* __restrict__ csr,
    int E, int N, int npr)
{
    const int grp = blockIdx.x & (NXCD - 1);
    const int bIn = blockIdx.x >> 3;
    const int nbk = gridDim.x >> 3;
    const int lo = grp * npr;
    const int hi = lo + npr;

    int i = bIn * 256 + threadIdx.x;
    const int stride = nbk * 256;
    for (int e = i; e < E; e += stride) {
        const int s = src[e];
        const int d = dst[e];
        if (d >= lo && d < hi) {            // fwd segment d owned by this group
            int p = atomicAdd(&cur[d], 1);
            csr[p] = s;
        }
        if (s >= lo && s < hi) {            // bwd segment N+s owned by this group
            int p = atomicAdd(&cur[N + s], 1);
            csr[p] = d;
        }
    }
}

// ---------------------------------------------------------------------------
// Phase B: gather means in bf16. 16 lanes per segment; lane l owns bf16
// columns [8l, 8l+8). Bounds from IMMUTABLE off.
// ---------------------------------------------------------------------------
__global__ __launch_bounds__(256) void gather_mean_kernel(
    const unsigned short* __restrict__ featb, const int* __restrict__ off,
    const int* __restrict__ csr, unsigned short* __restrict__ meanb, int n2)
{
    const int tid = blockIdx.x * 256 + threadIdx.x;
    const int seg = tid >> 4;
    const int l = tid & 15;
    if (seg >= n2) return;

    const int beg = off[seg], end = off[seg + 1];
    float a0=0,a1=0,a2=0,a3=0,a4=0,a5=0,a6=0,a7=0;

    int e = beg;
    for (; e + 1 < end; e += 2) {
        const int n0 = csr[e], n1 = csr[e + 1];
        const uint4 v0 = *reinterpret_cast<const uint4*>(featb + (size_t)n0 * D + l * 8);
        const uint4 v1 = *reinterpret_cast<const uint4*>(featb + (size_t)n1 * D + l * 8);
        a0 += bflo(v0.x) + bflo(v1.x); a1 += bfhi(v0.x) + bfhi(v1.x);
        a2 += bflo(v0.y) + bflo(v1.y); a3 += bfhi(v0.y) + bfhi(v1.y);
        a4 += bflo(v0.z) + bflo(v1.z); a5 += bfhi(v0.z) + bfhi(v1.z);
        a6 += bflo(v0.w) + bflo(v1.w); a7 += bfhi(v0.w) + bfhi(v1.w);
    }
    if (e < end) {
        const int n0 = csr[e];
        const uint4 v0 = *reinterpret_cast<const uint4*>(featb + (size_t)n0 * D + l * 8);
        a0 += bflo(v0.x); a1 += bfhi(v0.x);
        a2 += bflo(v0.y); a3 += bfhi(v0.y);
        a4 += bflo(v0.z); a5 += bfhi(v0.z);
        a6 += bflo(v0.w); a7 += bfhi(v0.w);
    }

    const int deg = end - beg;
    const float inv = 1.0f / (float)((deg > 1) ? deg : 1);
    uint4 o;
    o.x = pack2bf(a0 * inv, a1 * inv);
    o.y = pack2bf(a2 * inv, a3 * inv);
    o.z = pack2bf(a4 * inv, a5 * inv);
    o.w = pack2bf(a6 * inv, a7 * inv);
    *reinterpret_cast<uint4*>(meanb + (size_t)seg * D + l * 8) = o;
}

// ---------------------------------------------------------------------------
// Phase C: bf16 MFMA GEMM (m89-verified C/D layout).
// ---------------------------------------------------------------------------
__global__ __launch_bounds__(256) void mfma_gemm_kernel(
    const unsigned short* __restrict__ featb,
    const unsigned short* __restrict__ meanb,
    const unsigned short* __restrict__ Wb,      // [128][384] bf16
    float* __restrict__ out, int N)
{
    const int t = threadIdx.x;
    const int wv = t >> 6;
    const int lane = t & 63;
    const int r = lane & 15;
    const int kb = (lane >> 4) * 8;

    const int row0 = blockIdx.x * 64 + wv * 16;
    const int row = row0 + r;
    const int rowc = (row < N) ? row : (N - 1);

    f32x4 acc[8];
#pragma unroll
    for (int n = 0; n < 8; ++n) acc[n] = (f32x4){0.f, 0.f, 0.f, 0.f};

    const unsigned short* h0 = featb + (size_t)rowc * D;
    const unsigned short* h1 = meanb + (size_t)rowc * D;
    const unsigned short* h2 = meanb + ((size_t)N + rowc) * D;

#pragma unroll
    for (int k0 = 0; k0 < 384; k0 += 32) {
        const unsigned short* hs = (k0 < 128) ? h0 : (k0 < 256) ? h1 : h2;
        const int ko = (k0 & 127) + kb;
        const bf16x8 a = *reinterpret_cast<const bf16x8*>(hs + ko);
#pragma unroll
        for (int n = 0; n < 8; ++n) {
            const int c = n * 16 + r;
            const bf16x8 b = *reinterpret_cast<const bf16x8*>(Wb + (size_t)c * 384 + k0 + kb);
            acc[n] = __builtin_amdgcn_mfma_f32_16x16x32_bf16(a, b, acc[n], 0, 0, 0);
        }
    }

    const int ro = row0 + (lane >> 4) * 4;
#pragma unroll
    for (int n = 0; n < 8; ++n) {
        const int c = n * 16 + r;
#pragma unroll
        for (int i = 0; i < 4; ++i) {
            const int rr2 = ro + i;
            if (rr2 < N) out[(size_t)rr2 * D + c] = fmaxf(acc[n][i], 0.0f);
        }
    }
}

// ---------------------------------------------------------------------------
extern "C" void kernel_launch(void* const* d_in, const int* in_sizes, int n_in,
                              void* d_out, int out_size, void* d_ws, size_t ws_size,
                              hipStream_t stream) {
    const float* feat = (const float*)d_in[0];
    const float* W    = (const float*)d_in[1];
    const int*   ei   = (const int*)d_in[2];
    float*       out  = (float*)d_out;

    const int E = in_sizes[2] / 2;           // 800000
    const int N = in_sizes[0] / D;           // 100000
    const int n2 = 2 * N;
    const int* src = ei;
    const int* dst = ei + E;

    // ws layout (4B units then 2B units, all 16B-aligned):
    // cnt[n2] | cur[n2] | off[n2+4] | blk[256] | csr[2E] |
    // featb[N*D] u16 | Wb[128*384] u16 | meanb[n2*D] u16
    int* cnt = (int*)d_ws;
    int* cur = cnt + n2;
    int* off = cur + n2;
    int* blk = off + (n2 + 4);
    int* csr = blk + 256;
    unsigned short* featb = (unsigned short*)(csr + 2 * E);
    unsigned short* Wb    = featb + (size_t)N * D;
    unsigned short* meanb = Wb + 128 * 384;

    // zero cnt only (cur and off are fully initialized by scan3)
    hipMemsetAsync(cnt, 0, (size_t)n2 * sizeof(int), stream);

    const int NB = (n2 + CHUNK - 1) / CHUNK; // 196
    const int npr = (N + NXCD - 1) / NXCD;   // 12500 nodes per range

    tobf16_kernel<<<2048, 256, 0, stream>>>(feat, featb, N * D / 4);
    tobf16_kernel<<<48, 256, 0, stream>>>(W, Wb, 128 * 384 / 4);

    hist_kernel<<<2048, 256, 0, stream>>>(src, dst, cnt, E, N);
    scan1_kernel<<<NB, 256, 0, stream>>>(cnt, blk, n2);
    scan2_kernel<<<1, 256, 0, stream>>>(blk, NB);
    scan3_kernel<<<NB, 256, 0, stream>>>(cnt, blk, off, cur, n2, 2 * E);
    scatter_ids_kernel<<<2048, 256, 0, stream>>>(src, dst, cur, csr, E, N, npr);

    const int gather_blocks = (n2 * 16 + 255) / 256;   // 16 lanes per segment
    gather_mean_kernel<<<gather_blocks, 256, 0, stream>>>(featb, off, csr, meanb, n2);

    mfma_gemm_kernel<<<(N + 63) / 64, 256, 0, stream>>>(featb, meanb, Wb, out, N);
}